// Round 1
// baseline (483.949 us; speedup 1.0000x reference)
//
#include <hip/hip_runtime.h>
#include <stdint.h>

typedef unsigned short u16t;
typedef unsigned int   u32t;
typedef __attribute__((ext_vector_type(8))) short frag8;   // 8 bf16 = 4 VGPRs
typedef __attribute__((ext_vector_type(4))) float fragc;   // 4 fp32 acc

#define NN 50000
#define NE 800000
#define NB_EDGE 12500          // edge blocks (64 edges each)
#define NB_NODE 782            // node-MLP blocks (64 nodes each)

// packed-weight offsets in u16 elements within d_ws (weights: 139264 B)
#define W1P 0
#define W2P 24576
#define W3P 40960
#define U1P 49152
#define U2P 61440
// workspace byte offsets (all 16B-aligned)
#define NFB_OFF 139264                     // u16 nfb[NN*64]  (6.4 MB)
#define STB_OFF (NFB_OFF + 6400000)        // u16 stb[NN*32]  (3.2 MB)
#define CNT_OFF (STB_OFF + 3200000)        // u32 cnt[NN]     (200 KB)
#define PSD_OFF (CNT_OFF + 200000)         // int2 psd[NE]    (6.4 MB)
#define PE_OFF  (PSD_OFF + 6400000)        // u32 pe[NE]      (3.2 MB)

#define XST 200   // X tile row stride (192 + 8 pad) in bf16
#define HST 136   // hidden tile row stride (128 + 8 pad)
#define XSTN 104  // node X tile row stride (96 + 8 pad)
#define MST 65    // f32 message tile row stride (64 + 1 pad)

// prep grid partition
#define PB_PACK 34
#define PB_ZERO 3125           // zero out1: NN*16 float4
#define PB_NF   1563           // cvt nf: NN*64 = 3.2M elems, 2048/block
#define PB_ST   782            // cvt st: NN*32 = 1.6M elems
#define PB_HIST 3125           // dst histogram: NE edges

__device__ __forceinline__ u16t f2bf(float f) {
    u32t x = __builtin_bit_cast(u32t, f);
    x = x + 0x7FFFu + ((x >> 16) & 1u);   // RNE
    return (u16t)(x >> 16);
}

__device__ __forceinline__ u32t pack_bf2(float x, float y) {
#if __has_builtin(__builtin_amdgcn_cvt_pk_bf16_f32)
    typedef __attribute__((ext_vector_type(2))) __bf16 bfv2;
    bfv2 r = __builtin_amdgcn_cvt_pk_bf16_f32(x, y);
    return __builtin_bit_cast(u32t, r);
#else
    return (u32t)f2bf(x) | ((u32t)f2bf(y) << 16);
#endif
}

// ---------------------------------------------------------------------------
// Weight prepack core: W (K x N row-major fp32) -> bf16 B-frag order.
// ---------------------------------------------------------------------------
__device__ __forceinline__ void prepack_one(int t, const float* w1, const float* w2,
                                            const float* w3, const float* u1,
                                            const float* u2, u16t* out) {
    const float* src; u16t* dst; int id, K, N;
    if (t < 3072)      { id = t;        K = 192; N = 128; src = w1; dst = out + W1P; }
    else if (t < 5120) { id = t - 3072; K = 128; N = 128; src = w2; dst = out + W2P; }
    else if (t < 6144) { id = t - 5120; K = 128; N = 64;  src = w3; dst = out + W3P; }
    else if (t < 7680) { id = t - 6144; K = 96;  N = 128; src = u1; dst = out + U1P; }
    else if (t < 8704) { id = t - 7680; K = 128; N = 64;  src = u2; dst = out + U2P; }
    else return;
    int lane = id & 63;
    int fl   = id >> 6;
    int ksteps = K >> 5;
    int nb = fl / ksteps, ks = fl - nb * ksteps;
    int n  = nb * 16 + (lane & 15);
    int k0 = ks * 32 + (lane >> 4) * 8;
    const float* s = src + (size_t)k0 * N + n;
    uint4 v;
    v.x = pack_bf2(s[0],           s[(size_t)N]);
    v.y = pack_bf2(s[2*(size_t)N], s[3*(size_t)N]);
    v.z = pack_bf2(s[4*(size_t)N], s[5*(size_t)N]);
    v.w = pack_bf2(s[6*(size_t)N], s[7*(size_t)N]);
    *(uint4*)(dst + (size_t)id * 8) = v;
}

// fused prep: prepack weights | zero out1 | cvt nf->bf16 | cvt st->bf16 | dst hist
__global__ void prep_k(const float* __restrict__ w1, const float* __restrict__ w2,
                       const float* __restrict__ w3, const float* __restrict__ u1,
                       const float* __restrict__ u2, u16t* __restrict__ wp,
                       float4* __restrict__ out1v,
                       const float* __restrict__ nf, u16t* __restrict__ nfb,
                       const float* __restrict__ st, u16t* __restrict__ stb,
                       const int* __restrict__ eidx, u32t* __restrict__ cnt) {
    int b = blockIdx.x;
    if (b < PB_PACK) {
        prepack_one(b * 256 + threadIdx.x, w1, w2, w3, u1, u2, wp);
    } else if (b < PB_PACK + PB_ZERO) {
        int i = (b - PB_PACK) * 256 + threadIdx.x;
        if (i < NN * 16) out1v[i] = make_float4(0.f, 0.f, 0.f, 0.f);
    } else if (b < PB_PACK + PB_ZERO + PB_NF) {
        int i = ((b - PB_PACK - PB_ZERO) * 256 + threadIdx.x) * 8;
        if (i < NN * 64) {
            float4 a = *(const float4*)(nf + i);
            float4 c = *(const float4*)(nf + i + 4);
            uint4 v;
            v.x = pack_bf2(a.x, a.y); v.y = pack_bf2(a.z, a.w);
            v.z = pack_bf2(c.x, c.y); v.w = pack_bf2(c.z, c.w);
            *(uint4*)(nfb + i) = v;
        }
    } else if (b < PB_PACK + PB_ZERO + PB_NF + PB_ST) {
        int i = ((b - PB_PACK - PB_ZERO - PB_NF) * 256 + threadIdx.x) * 8;
        if (i < NN * 32) {
            float4 a = *(const float4*)(st + i);
            float4 c = *(const float4*)(st + i + 4);
            uint4 v;
            v.x = pack_bf2(a.x, a.y); v.y = pack_bf2(a.z, a.w);
            v.z = pack_bf2(c.x, c.y); v.w = pack_bf2(c.z, c.w);
            *(uint4*)(stb + i) = v;
        }
    } else {
        int i = (b - PB_PACK - PB_ZERO - PB_NF - PB_ST) * 256 + threadIdx.x;
        if (i < NE) atomicAdd(cnt + eidx[2 * i + 1], 1u);
    }
}

// exclusive prefix scan of cnt[0..NN) in place. Single block, 1024 threads.
__global__ void scan_k(u32t* __restrict__ cnt) {
    __shared__ u32t wsum[16];
    __shared__ u32t carry;
    const int tid = threadIdx.x;
    const int lane = tid & 63;
    const int wv = tid >> 6;
    if (tid == 0) carry = 0;
    __syncthreads();
    for (int c = 0; c < 49; ++c) {
        int i = c * 1024 + tid;
        u32t v = (i < NN) ? cnt[i] : 0u;
        u32t s = v;
        #pragma unroll
        for (int d = 1; d < 64; d <<= 1) {
            u32t t = __shfl_up(s, (unsigned)d, 64);
            if (lane >= d) s += t;
        }
        if (lane == 63) wsum[wv] = s;
        __syncthreads();                     // B1: wsum ready
        u32t wbase = 0;
        #pragma unroll
        for (int w = 0; w < 16; ++w) wbase += (w < wv) ? wsum[w] : 0u;
        if (i < NN) cnt[i] = carry + wbase + (s - v);
        u32t tot = 0;
        if (tid == 0) {
            #pragma unroll
            for (int w = 0; w < 16; ++w) tot += wsum[w];
        }
        __syncthreads();                     // B2: all reads of carry/wsum done
        if (tid == 0) carry += tot;
    }
}

// scatter edges into dst-sorted order: psd[pos]=(src,dst), pe[pos]=orig edge id
__global__ void scatter_k(const int* __restrict__ eidx, u32t* __restrict__ cnt,
                          int2* __restrict__ psd, u32t* __restrict__ pe) {
    int i = blockIdx.x * 256 + threadIdx.x;
    int s = eidx[2 * i];
    int d = eidx[2 * i + 1];
    u32t pos = atomicAdd(cnt + d, 1u);
    psd[pos] = make_int2(s, d);
    pe[pos]  = (u32t)i;
}

// ---------------------------------------------------------------------------
// Fused main kernel. Single 25.9 KB LDS region, 6 blocks/CU.
// Edge role: 64 dst-SORTED edges/block, 4 waves, MLP 192->128->128->64,
//   then LDS message buffer + wave-uniform segmented reduce -> few coalesced atomics.
// Node role: update MLP, out0 = nf + upd.
// ---------------------------------------------------------------------------
__global__ __launch_bounds__(256, 6)
void fused_k(const u16t* __restrict__ nfb, const u16t* __restrict__ stb,
             const float* __restrict__ nf, const float* __restrict__ ef,
             const float* __restrict__ b1, const float* __restrict__ b2,
             const float* __restrict__ b3, const float* __restrict__ ub1,
             const float* __restrict__ ub2,
             const int2* __restrict__ psd, const u32t* __restrict__ pe,
             const u16t* __restrict__ wp,
             float* __restrict__ out0, float* __restrict__ out1) {
    __shared__ __align__(16) u16t R[64 * XST];   // 25600 B: X, H, H', then f32 msgs
    __shared__ int dstL[64];
    const int tid = threadIdx.x;

    if (blockIdx.x >= NB_EDGE) {
        // ---------------- node role ----------------
        const int n0 = (blockIdx.x - NB_EDGE) * 64;
        { // stage [nfb|stb] copy, 4 threads/row, 3 uint4 chunks each
            int rl = tid >> 2, p = tid & 3;
            int nd = n0 + rl;
            const uint4* nsb = (const uint4*)(nfb + (size_t)nd * 64);
            const uint4* spb = (const uint4*)(stb + (size_t)nd * 32);
            u16t* xr = R + rl * XSTN;
            #pragma unroll
            for (int g = p; g < 12; g += 4) {
                uint4 v = make_uint4(0u, 0u, 0u, 0u);
                if (nd < NN) v = (g < 8) ? nsb[g] : spb[g - 8];
                *(uint4*)(xr + g * 8) = v;
            }
        }
        __syncthreads();
        const int lane = tid & 63;
        const int wv   = tid >> 6;
        const int m16  = wv * 16;
        const int lr   = lane & 15;
        const int qd   = lane >> 4;

        fragc acc[8];
        #pragma unroll
        for (int n = 0; n < 8; n++) acc[n] = (fragc){0.f, 0.f, 0.f, 0.f};
        {
            const frag8* w = (const frag8*)(wp + U1P);
            #pragma unroll
            for (int ks = 0; ks < 3; ks++) {
                frag8 a = *(const frag8*)(R + (m16 + lr) * XSTN + ks * 32 + qd * 8);
                #pragma unroll
                for (int n = 0; n < 8; n++)
                    acc[n] = __builtin_amdgcn_mfma_f32_16x16x32_bf16(
                        a, w[(n * 3 + ks) * 64 + lane], acc[n], 0, 0, 0);
            }
        }
        __syncthreads();   // X consumed before H overwrite
        #pragma unroll
        for (int n = 0; n < 8; n++) {
            float bs = ub1[n * 16 + lr];
            #pragma unroll
            for (int r = 0; r < 4; r++) {
                float v = acc[n][r] + bs;
                R[(m16 + qd * 4 + r) * HST + n * 16 + lr] = f2bf(v > 0.f ? v : 0.f);
            }
        }
        __syncthreads();

        fragc a2[4];
        #pragma unroll
        for (int n = 0; n < 4; n++) a2[n] = (fragc){0.f, 0.f, 0.f, 0.f};
        {
            const frag8* w = (const frag8*)(wp + U2P);
            #pragma unroll
            for (int ks = 0; ks < 4; ks++) {
                frag8 a = *(const frag8*)(R + (m16 + lr) * HST + ks * 32 + qd * 8);
                #pragma unroll
                for (int n = 0; n < 4; n++)
                    a2[n] = __builtin_amdgcn_mfma_f32_16x16x32_bf16(
                        a, w[(n * 4 + ks) * 64 + lane], a2[n], 0, 0, 0);
            }
        }
        #pragma unroll
        for (int n = 0; n < 4; n++) {
            float bs = ub2[n * 16 + lr];
            #pragma unroll
            for (int r = 0; r < 4; r++) {
                int nd = n0 + m16 + qd * 4 + r;
                if (nd < NN) {
                    int col = n * 16 + lr;
                    out0[(size_t)nd * 64 + col] = nf[(size_t)nd * 64 + col] + a2[n][r] + bs;
                }
            }
        }
        return;
    }

    // ---------------- edge role ----------------
    const int e0 = blockIdx.x * 64;

    { // stage X: bf16 copies (nf[s]|nf[d]|st[s]) + ef fp32->bf16 (orig-id gather)
        int el = tid >> 2, p = tid & 3;
        int i = e0 + el;
        int2 sd = psd[i];
        int s = sd.x, d = sd.y;
        int e = (int)pe[i];
        const uint4* nsb = (const uint4*)(nfb + (size_t)s * 64);
        const uint4* ndb = (const uint4*)(nfb + (size_t)d * 64);
        const uint4* spb = (const uint4*)(stb + (size_t)s * 32);
        u16t* xr = R + el * XST;
        #pragma unroll
        for (int g = p; g < 20; g += 4) {   // 16B bf16 chunks: cols 0..127, 160..191
            uint4 v;
            if (g < 8)       v = nsb[g];
            else if (g < 16) v = ndb[g - 8];
            else             v = spb[g - 16];
            *(uint4*)(xr + (g < 16 ? g * 8 : 160 + (g - 16) * 8)) = v;
        }
        const float4* epf = (const float4*)(ef + (size_t)e * 32);
        #pragma unroll
        for (int h = p; h < 8; h += 4) {    // ef: cols 128..159
            float4 v = epf[h];
            uint2 pk;
            pk.x = pack_bf2(v.x, v.y);
            pk.y = pack_bf2(v.z, v.w);
            *(uint2*)(xr + 128 + h * 4) = pk;
        }
    }
    if (tid < 64) dstL[tid] = psd[e0 + tid].y;
    __syncthreads();             // B1: X + dstL visible

    const int lane = tid & 63;
    const int wv   = tid >> 6;
    const int lr   = lane & 15;
    const int qd   = lane >> 4;
    const int nb0  = 2 * wv, nb1 = 2 * wv + 1;

    // ---- layer 1: X(64x192) @ W1(192x128); wave computes 32 cols
    fragc acc[2][4];
    #pragma unroll
    for (int i = 0; i < 2; i++)
        #pragma unroll
        for (int m = 0; m < 4; m++) acc[i][m] = (fragc){0.f, 0.f, 0.f, 0.f};
    {
        const frag8* w = (const frag8*)(wp + W1P);
        #pragma unroll
        for (int ks = 0; ks < 6; ks++) {
            frag8 w0 = w[(nb0 * 6 + ks) * 64 + lane];
            frag8 w1 = w[(nb1 * 6 + ks) * 64 + lane];
            #pragma unroll
            for (int m = 0; m < 4; m++) {
                frag8 a = *(const frag8*)(R + (m * 16 + lr) * XST + ks * 32 + qd * 8);
                acc[0][m] = __builtin_amdgcn_mfma_f32_16x16x32_bf16(a, w0, acc[0][m], 0, 0, 0);
                acc[1][m] = __builtin_amdgcn_mfma_f32_16x16x32_bf16(a, w1, acc[1][m], 0, 0, 0);
            }
        }
    }
    __syncthreads();             // B2: all X reads done, R reusable
    #pragma unroll
    for (int i = 0; i < 2; i++) {
        int nb = nb0 + i;
        float bs = b1[nb * 16 + lr];
        #pragma unroll
        for (int m = 0; m < 4; m++)
            #pragma unroll
            for (int r = 0; r < 4; r++) {
                float v = acc[i][m][r] + bs;
                R[(m * 16 + qd * 4 + r) * HST + nb * 16 + lr] = f2bf(v > 0.f ? v : 0.f);
            }
    }
    __syncthreads();             // B3: H complete

    // ---- layer 2: H(64x128) @ W2(128x128)
    #pragma unroll
    for (int i = 0; i < 2; i++)
        #pragma unroll
        for (int m = 0; m < 4; m++) acc[i][m] = (fragc){0.f, 0.f, 0.f, 0.f};
    {
        const frag8* w = (const frag8*)(wp + W2P);
        #pragma unroll
        for (int ks = 0; ks < 4; ks++) {
            frag8 w0 = w[(nb0 * 4 + ks) * 64 + lane];
            frag8 w1 = w[(nb1 * 4 + ks) * 64 + lane];
            #pragma unroll
            for (int m = 0; m < 4; m++) {
                frag8 a = *(const frag8*)(R + (m * 16 + lr) * HST + ks * 32 + qd * 8);
                acc[0][m] = __builtin_amdgcn_mfma_f32_16x16x32_bf16(a, w0, acc[0][m], 0, 0, 0);
                acc[1][m] = __builtin_amdgcn_mfma_f32_16x16x32_bf16(a, w1, acc[1][m], 0, 0, 0);
            }
        }
    }
    __syncthreads();             // B4: all H reads done
    #pragma unroll
    for (int i = 0; i < 2; i++) {
        int nb = nb0 + i;
        float bs = b2[nb * 16 + lr];
        #pragma unroll
        for (int m = 0; m < 4; m++)
            #pragma unroll
            for (int r = 0; r < 4; r++) {
                float v = acc[i][m][r] + bs;
                R[(m * 16 + qd * 4 + r) * HST + nb * 16 + lr] = f2bf(v > 0.f ? v : 0.f);
            }
    }
    __syncthreads();             // B5: H' complete

    // ---- layer 3: H'(64x128) @ W3(128x64); wave owns N-block wv (16 cols)
    fragc a3[4];
    #pragma unroll
    for (int m = 0; m < 4; m++) a3[m] = (fragc){0.f, 0.f, 0.f, 0.f};
    {
        const frag8* w = (const frag8*)(wp + W3P);
        #pragma unroll
        for (int ks = 0; ks < 4; ks++) {
            frag8 wf = w[(wv * 4 + ks) * 64 + lane];
            #pragma unroll
            for (int m = 0; m < 4; m++) {
                frag8 a = *(const frag8*)(R + (m * 16 + lr) * HST + ks * 32 + qd * 8);
                a3[m] = __builtin_amdgcn_mfma_f32_16x16x32_bf16(a, wf, a3[m], 0, 0, 0);
            }
        }
    }
    __syncthreads();             // B6: H' reads done, R reusable as f32 msg buffer

    // ---- epilogue: messages -> LDS f32, then wave-uniform segmented reduce
    float* Rf = (float*)R;       // 64 x MST f32 (16.6 KB of the 25.6 KB region)
    {
        float bs = b3[wv * 16 + lr];
        #pragma unroll
        for (int m = 0; m < 4; m++)
            #pragma unroll
            for (int r = 0; r < 4; r++)
                Rf[(m * 16 + qd * 4 + r) * MST + wv * 16 + lr] = a3[m][r] + bs;
    }
    __syncthreads();             // B7: msg tile complete
    {
        // wave wv owns rows [wv*16, wv*16+16); lane = column. dst sorted ->
        // run-boundary branch is wave-uniform; each flush is a 64x4B coalesced atomic.
        const int c  = tid & 63;
        const int r0 = (tid >> 6) * 16;
        float a = Rf[r0 * MST + c];
        int d = dstL[r0];
        for (int r = r0 + 1; r < r0 + 16; ++r) {
            int dn = dstL[r];
            float v = Rf[r * MST + c];
            if (dn == d) {
                a += v;
            } else {
                atomicAdd(out1 + (size_t)d * 64 + c, a);
                d = dn; a = v;
            }
        }
        atomicAdd(out1 + (size_t)d * 64 + c, a);
    }
}

extern "C" void kernel_launch(void* const* d_in, const int* in_sizes, int n_in,
                              void* d_out, int out_size, void* d_ws, size_t ws_size,
                              hipStream_t stream) {
    const float* nf  = (const float*)d_in[0];
    const float* ef  = (const float*)d_in[1];
    const float* st  = (const float*)d_in[2];
    const float* mW1 = (const float*)d_in[3];
    const float* mb1 = (const float*)d_in[4];
    const float* mW2 = (const float*)d_in[5];
    const float* mb2 = (const float*)d_in[6];
    const float* mW3 = (const float*)d_in[7];
    const float* mb3 = (const float*)d_in[8];
    const float* uW1 = (const float*)d_in[9];
    const float* ub1 = (const float*)d_in[10];
    const float* uW2 = (const float*)d_in[11];
    const float* ub2 = (const float*)d_in[12];
    const int*  eidx = (const int*)d_in[13];

    float* out0 = (float*)d_out;
    float* out1 = out0 + (size_t)NN * 64;
    char*  ws   = (char*)d_ws;
    u16t*  wp   = (u16t*)ws;
    u16t*  nfb  = (u16t*)(ws + NFB_OFF);
    u16t*  stb  = (u16t*)(ws + STB_OFF);
    u32t*  cnt  = (u32t*)(ws + CNT_OFF);
    int2*  psd  = (int2*)(ws + PSD_OFF);
    u32t*  pe   = (u32t*)(ws + PE_OFF);

    hipMemsetAsync(cnt, 0, NN * sizeof(u32t), stream);
    prep_k<<<PB_PACK + PB_ZERO + PB_NF + PB_ST + PB_HIST, 256, 0, stream>>>(
        mW1, mW2, mW3, uW1, uW2, wp, (float4*)out1, nf, nfb, st, stb, eidx, cnt);
    scan_k<<<1, 1024, 0, stream>>>(cnt);
    scatter_k<<<NE / 256, 256, 0, stream>>>(eidx, cnt, psd, pe);
    fused_k<<<NB_EDGE + NB_NODE, 256, 0, stream>>>(
        nfb, stb, nf, ef, mb1, mb2, mb3, ub1, ub2, psd, pe, wp, out0, out1);
}

// Round 2
// 481.425 us; speedup vs baseline: 1.0052x; 1.0052x over previous
//
#include <hip/hip_runtime.h>
#include <stdint.h>

typedef unsigned short u16t;
typedef unsigned int   u32t;
typedef __attribute__((ext_vector_type(8))) short frag8;   // 8 bf16 = 4 VGPRs
typedef __attribute__((ext_vector_type(4))) float fragc;   // 4 fp32 acc

#define NN 50000
#define NE 800000
#define EB 48                  // edges per block (3 m-tiles)
#define NB_EDGE 16667          // ceil(NE/48); last block has 32 valid edges
#define NB_NODE 782            // node-MLP blocks (64 nodes each)

// packed-weight offsets in u16 elements within d_ws (weights: 139264 B)
#define W1P 0
#define W2P 24576
#define W3P 40960
#define U1P 49152
#define U2P 61440
// bf16 mirrors of nf/st in d_ws (byte offsets; both 16B-aligned)
#define NFB_OFF 139264                     // u16 nfb[NN*64]  (6.4 MB)
#define STB_OFF (NFB_OFF + 6400000)        // u16 stb[NN*32]  (3.2 MB)

// prep grid partition
#define PB_PACK 34
#define PB_ZERO 3125           // zero out1: NN*16 float4
#define PB_NF   1563           // cvt nf: NN*64 = 3.2M elems, 2048/block
#define PB_ST   782            // cvt st: NN*32 = 1.6M elems

__device__ __forceinline__ u16t f2bf(float f) {
    u32t x = __builtin_bit_cast(u32t, f);
    x = x + 0x7FFFu + ((x >> 16) & 1u);   // RNE
    return (u16t)(x >> 16);
}

__device__ __forceinline__ u32t pack_bf2(float x, float y) {
#if __has_builtin(__builtin_amdgcn_cvt_pk_bf16_f32)
    typedef __attribute__((ext_vector_type(2))) __bf16 bfv2;
    bfv2 r = __builtin_amdgcn_cvt_pk_bf16_f32(x, y);
    return __builtin_bit_cast(u32t, r);
#else
    return (u32t)f2bf(x) | ((u32t)f2bf(y) << 16);
#endif
}

// ---------------------------------------------------------------------------
// Weight prepack core: W (K x N row-major fp32) -> bf16 B-frag order.
// ---------------------------------------------------------------------------
__device__ __forceinline__ void prepack_one(int t, const float* w1, const float* w2,
                                            const float* w3, const float* u1,
                                            const float* u2, u16t* out) {
    const float* src; u16t* dst; int id, K, N;
    if (t < 3072)      { id = t;        K = 192; N = 128; src = w1; dst = out + W1P; }
    else if (t < 5120) { id = t - 3072; K = 128; N = 128; src = w2; dst = out + W2P; }
    else if (t < 6144) { id = t - 5120; K = 128; N = 64;  src = w3; dst = out + W3P; }
    else if (t < 7680) { id = t - 6144; K = 96;  N = 128; src = u1; dst = out + U1P; }
    else if (t < 8704) { id = t - 7680; K = 128; N = 64;  src = u2; dst = out + U2P; }
    else return;
    int lane = id & 63;
    int fl   = id >> 6;
    int ksteps = K >> 5;
    int nb = fl / ksteps, ks = fl - nb * ksteps;
    int n  = nb * 16 + (lane & 15);
    int k0 = ks * 32 + (lane >> 4) * 8;
    const float* s = src + (size_t)k0 * N + n;
    uint4 v;
    v.x = pack_bf2(s[0],           s[(size_t)N]);
    v.y = pack_bf2(s[2*(size_t)N], s[3*(size_t)N]);
    v.z = pack_bf2(s[4*(size_t)N], s[5*(size_t)N]);
    v.w = pack_bf2(s[6*(size_t)N], s[7*(size_t)N]);
    *(uint4*)(dst + (size_t)id * 8) = v;
}

// fused prep: prepack weights | zero out1 | cvt nf->bf16 | cvt st->bf16
__global__ void prep_k(const float* __restrict__ w1, const float* __restrict__ w2,
                       const float* __restrict__ w3, const float* __restrict__ u1,
                       const float* __restrict__ u2, u16t* __restrict__ wp,
                       float4* __restrict__ out1v,
                       const float* __restrict__ nf, u16t* __restrict__ nfb,
                       const float* __restrict__ st, u16t* __restrict__ stb) {
    int b = blockIdx.x;
    if (b < PB_PACK) {
        prepack_one(b * 256 + threadIdx.x, w1, w2, w3, u1, u2, wp);
    } else if (b < PB_PACK + PB_ZERO) {
        int i = (b - PB_PACK) * 256 + threadIdx.x;
        if (i < NN * 16) out1v[i] = make_float4(0.f, 0.f, 0.f, 0.f);
    } else if (b < PB_PACK + PB_ZERO + PB_NF) {
        int i = ((b - PB_PACK - PB_ZERO) * 256 + threadIdx.x) * 8;
        if (i < NN * 64) {
            float4 a = *(const float4*)(nf + i);
            float4 c = *(const float4*)(nf + i + 4);
            uint4 v;
            v.x = pack_bf2(a.x, a.y); v.y = pack_bf2(a.z, a.w);
            v.z = pack_bf2(c.x, c.y); v.w = pack_bf2(c.z, c.w);
            *(uint4*)(nfb + i) = v;
        }
    } else {
        int i = ((b - PB_PACK - PB_ZERO - PB_NF) * 256 + threadIdx.x) * 8;
        if (i < NN * 32) {
            float4 a = *(const float4*)(st + i);
            float4 c = *(const float4*)(st + i + 4);
            uint4 v;
            v.x = pack_bf2(a.x, a.y); v.y = pack_bf2(a.z, a.w);
            v.z = pack_bf2(c.x, c.y); v.w = pack_bf2(c.z, c.w);
            *(uint4*)(stb + i) = v;
        }
    }
}

// ---------------------------------------------------------------------------
// Fused main kernel. LDS 18.6 KB -> 8 blocks/CU (100% wave occupancy).
// Conflict-free chunk-XOR-swizzled LDS tiles (natural strides, no pads):
//   16B chunk c of row stored at c ^ (row & 7)  [2-way max on ds_read_b128].
// Edge role: 48 edges/block, 4 waves, N-partitioned MLP 192->128->128->64,
//   direct per-lane atomic scatter (proven non-binding in R1).
// Node role: update MLP, out0 = nf + upd.
// ---------------------------------------------------------------------------
__global__ __launch_bounds__(256, 8)
void fused_k(const u16t* __restrict__ nfb, const u16t* __restrict__ stb,
             const float* __restrict__ nf, const float* __restrict__ ef,
             const float* __restrict__ b1, const float* __restrict__ b2,
             const float* __restrict__ b3, const float* __restrict__ ub1,
             const float* __restrict__ ub2, const int* __restrict__ eidx,
             const u16t* __restrict__ wp,
             float* __restrict__ out0, float* __restrict__ out1) {
    // edge X: 48 rows x 24 chunks (192 u16/row) = 18432 B
    // edge H: 48 rows x 16 chunks (128 u16/row) = 12288 B (overlaps X region)
    // node X: 64 x 12 chunks (96 u16/row); node H: 64 x 16 chunks
    __shared__ __align__(16) u16t R[EB * 192];
    __shared__ int dstL[EB];
    const int tid = threadIdx.x;

    if (blockIdx.x >= NB_EDGE) {
        // ---------------- node role ----------------
        const int n0 = (blockIdx.x - NB_EDGE) * 64;
        { // stage [nfb|stb], 4 threads/row, swizzled chunks
            int rl = tid >> 2, p = tid & 3;
            int nd = n0 + rl;
            const uint4* nsb = (const uint4*)(nfb + (size_t)nd * 64);
            const uint4* spb = (const uint4*)(stb + (size_t)nd * 32);
            #pragma unroll
            for (int g = p; g < 12; g += 4) {
                uint4 v = make_uint4(0u, 0u, 0u, 0u);
                if (nd < NN) v = (g < 8) ? nsb[g] : spb[g - 8];
                int swc = (g < 8) ? (g ^ (rl & 7)) : (g ^ (rl & 3));
                *(uint4*)(R + rl * 96 + (swc << 3)) = v;
            }
        }
        __syncthreads();
        const int lane = tid & 63;
        const int wv   = tid >> 6;
        const int m16  = wv * 16;
        const int lr   = lane & 15;
        const int qd   = lane >> 4;
        const int sw   = lr & 7;

        fragc acc[8];
        #pragma unroll
        for (int n = 0; n < 8; n++) acc[n] = (fragc){0.f, 0.f, 0.f, 0.f};
        {
            const frag8* w = (const frag8*)(wp + U1P);
            #pragma unroll
            for (int ks = 0; ks < 3; ks++) {
                int c = ks * 4 + qd;
                int swc = (c < 8) ? (c ^ sw) : (c ^ (lr & 3));
                frag8 a = *(const frag8*)(R + (m16 + lr) * 96 + (swc << 3));
                #pragma unroll
                for (int n = 0; n < 8; n++)
                    acc[n] = __builtin_amdgcn_mfma_f32_16x16x32_bf16(
                        a, w[(n * 3 + ks) * 64 + lane], acc[n], 0, 0, 0);
            }
        }
        __syncthreads();   // X consumed before H overwrite
        #pragma unroll
        for (int n = 0; n < 8; n++) {
            float bs = ub1[n * 16 + lr];
            int cb = 2 * n + (lr >> 3);
            #pragma unroll
            for (int r = 0; r < 4; r++) {
                int row = m16 + qd * 4 + r;
                float v = acc[n][r] + bs;
                R[row * 128 + ((cb ^ (row & 7)) << 3) + (lr & 7)] = f2bf(v > 0.f ? v : 0.f);
            }
        }
        __syncthreads();

        fragc a2[4];
        #pragma unroll
        for (int n = 0; n < 4; n++) a2[n] = (fragc){0.f, 0.f, 0.f, 0.f};
        {
            const frag8* w = (const frag8*)(wp + U2P);
            #pragma unroll
            for (int ks = 0; ks < 4; ks++) {
                int c = ks * 4 + qd;
                frag8 a = *(const frag8*)(R + (m16 + lr) * 128 + ((c ^ sw) << 3));
                #pragma unroll
                for (int n = 0; n < 4; n++)
                    a2[n] = __builtin_amdgcn_mfma_f32_16x16x32_bf16(
                        a, w[(n * 4 + ks) * 64 + lane], a2[n], 0, 0, 0);
            }
        }
        #pragma unroll
        for (int n = 0; n < 4; n++) {
            float bs = ub2[n * 16 + lr];
            #pragma unroll
            for (int r = 0; r < 4; r++) {
                int nd = n0 + m16 + qd * 4 + r;
                if (nd < NN) {
                    int col = n * 16 + lr;
                    out0[(size_t)nd * 64 + col] = nf[(size_t)nd * 64 + col] + a2[n][r] + bs;
                }
            }
        }
        return;
    }

    // ---------------- edge role ----------------
    const int e0 = blockIdx.x * EB;

    { // stage X: chunk-linear, swizzled. chunks 0..15 = nfb[s]|nfb[d], 20..23 = stb[s]
        for (int id = tid; id < EB * 20; id += 256) {
            int row = id / 20;
            int g   = id - row * 20;
            int e   = e0 + row;
            uint4 v = make_uint4(0u, 0u, 0u, 0u);
            if (e < NE) {
                if (g < 16) {
                    int node = eidx[2 * e + (g >> 3)];
                    v = *(const uint4*)(nfb + (size_t)node * 64 + (g & 7) * 8);
                } else {
                    int s = eidx[2 * e];
                    v = *(const uint4*)(stb + (size_t)s * 32 + (g - 16) * 8);
                }
            }
            int c = (g < 16) ? g : (g + 4);
            *(uint4*)(R + row * 192 + ((c ^ (row & 7)) << 3)) = v;
        }
        // ef fp32 -> bf16, chunks 16..19 (8B half-chunks)
        for (int id = tid; id < EB * 8; id += 256) {
            int row = id >> 3, h = id & 7;
            int e = e0 + row;
            uint2 pk = make_uint2(0u, 0u);
            if (e < NE) {
                float4 v = *(const float4*)(ef + (size_t)e * 32 + h * 4);
                pk.x = pack_bf2(v.x, v.y);
                pk.y = pack_bf2(v.z, v.w);
            }
            int c = 16 + (h >> 1);
            *(uint2*)(R + row * 192 + ((c ^ (row & 7)) << 3) + (h & 1) * 4) = pk;
        }
        if (tid < EB) dstL[tid] = (e0 + tid < NE) ? eidx[2 * (e0 + tid) + 1] : 0;
    }
    __syncthreads();             // B1: X + dstL visible

    const int lane = tid & 63;
    const int wv   = tid >> 6;
    const int lr   = lane & 15;
    const int qd   = lane >> 4;
    const int sw   = lr & 7;
    const int nb0  = 2 * wv, nb1 = 2 * wv + 1;

    // ---- layer 1: X(48x192) @ W1(192x128); wave computes 32 cols
    fragc acc[2][3];
    #pragma unroll
    for (int i = 0; i < 2; i++)
        #pragma unroll
        for (int m = 0; m < 3; m++) acc[i][m] = (fragc){0.f, 0.f, 0.f, 0.f};
    {
        const frag8* w = (const frag8*)(wp + W1P);
        #pragma unroll
        for (int ks = 0; ks < 6; ks++) {
            frag8 w0 = w[(nb0 * 6 + ks) * 64 + lane];
            frag8 w1 = w[(nb1 * 6 + ks) * 64 + lane];
            int c = ks * 4 + qd;
            #pragma unroll
            for (int m = 0; m < 3; m++) {
                frag8 a = *(const frag8*)(R + (m * 16 + lr) * 192 + ((c ^ sw) << 3));
                acc[0][m] = __builtin_amdgcn_mfma_f32_16x16x32_bf16(a, w0, acc[0][m], 0, 0, 0);
                acc[1][m] = __builtin_amdgcn_mfma_f32_16x16x32_bf16(a, w1, acc[1][m], 0, 0, 0);
            }
        }
    }
    __syncthreads();             // B2: all X reads done, R reusable
    #pragma unroll
    for (int i = 0; i < 2; i++) {
        int nb = nb0 + i;
        float bs = b1[nb * 16 + lr];
        int cb = 2 * nb + (lr >> 3);
        #pragma unroll
        for (int m = 0; m < 3; m++)
            #pragma unroll
            for (int r = 0; r < 4; r++) {
                int row = m * 16 + qd * 4 + r;
                float v = acc[i][m][r] + bs;
                R[row * 128 + ((cb ^ (row & 7)) << 3) + (lr & 7)] = f2bf(v > 0.f ? v : 0.f);
            }
    }
    __syncthreads();             // B3: H complete

    // ---- layer 2: H(48x128) @ W2(128x128)
    #pragma unroll
    for (int i = 0; i < 2; i++)
        #pragma unroll
        for (int m = 0; m < 3; m++) acc[i][m] = (fragc){0.f, 0.f, 0.f, 0.f};
    {
        const frag8* w = (const frag8*)(wp + W2P);
        #pragma unroll
        for (int ks = 0; ks < 4; ks++) {
            frag8 w0 = w[(nb0 * 4 + ks) * 64 + lane];
            frag8 w1 = w[(nb1 * 4 + ks) * 64 + lane];
            int c = ks * 4 + qd;
            #pragma unroll
            for (int m = 0; m < 3; m++) {
                frag8 a = *(const frag8*)(R + (m * 16 + lr) * 128 + ((c ^ sw) << 3));
                acc[0][m] = __builtin_amdgcn_mfma_f32_16x16x32_bf16(a, w0, acc[0][m], 0, 0, 0);
                acc[1][m] = __builtin_amdgcn_mfma_f32_16x16x32_bf16(a, w1, acc[1][m], 0, 0, 0);
            }
        }
    }
    __syncthreads();             // B4: all H reads done
    #pragma unroll
    for (int i = 0; i < 2; i++) {
        int nb = nb0 + i;
        float bs = b2[nb * 16 + lr];
        int cb = 2 * nb + (lr >> 3);
        #pragma unroll
        for (int m = 0; m < 3; m++)
            #pragma unroll
            for (int r = 0; r < 4; r++) {
                int row = m * 16 + qd * 4 + r;
                float v = acc[i][m][r] + bs;
                R[row * 128 + ((cb ^ (row & 7)) << 3) + (lr & 7)] = f2bf(v > 0.f ? v : 0.f);
            }
    }
    __syncthreads();             // B5: H' complete

    // ---- layer 3: H'(48x128) @ W3(128x64); wave owns N-block wv (16 cols)
    fragc a3[3];
    #pragma unroll
    for (int m = 0; m < 3; m++) a3[m] = (fragc){0.f, 0.f, 0.f, 0.f};
    {
        const frag8* w = (const frag8*)(wp + W3P);
        #pragma unroll
        for (int ks = 0; ks < 4; ks++) {
            frag8 wf = w[(wv * 4 + ks) * 64 + lane];
            int c = ks * 4 + qd;
            #pragma unroll
            for (int m = 0; m < 3; m++) {
                frag8 a = *(const frag8*)(R + (m * 16 + lr) * 128 + ((c ^ sw) << 3));
                a3[m] = __builtin_amdgcn_mfma_f32_16x16x32_bf16(a, wf, a3[m], 0, 0, 0);
            }
        }
    }
    // ---- epilogue: scalar atomic scatter-add straight from registers
    {
        float bs = b3[wv * 16 + lr];
        #pragma unroll
        for (int m = 0; m < 3; m++)
            #pragma unroll
            for (int r = 0; r < 4; r++) {
                int row = m * 16 + qd * 4 + r;
                if (e0 + row < NE)
                    atomicAdd(out1 + (size_t)dstL[row] * 64 + wv * 16 + lr,
                              a3[m][r] + bs);
            }
    }
}

extern "C" void kernel_launch(void* const* d_in, const int* in_sizes, int n_in,
                              void* d_out, int out_size, void* d_ws, size_t ws_size,
                              hipStream_t stream) {
    const float* nf  = (const float*)d_in[0];
    const float* ef  = (const float*)d_in[1];
    const float* st  = (const float*)d_in[2];
    const float* mW1 = (const float*)d_in[3];
    const float* mb1 = (const float*)d_in[4];
    const float* mW2 = (const float*)d_in[5];
    const float* mb2 = (const float*)d_in[6];
    const float* mW3 = (const float*)d_in[7];
    const float* mb3 = (const float*)d_in[8];
    const float* uW1 = (const float*)d_in[9];
    const float* ub1 = (const float*)d_in[10];
    const float* uW2 = (const float*)d_in[11];
    const float* ub2 = (const float*)d_in[12];
    const int*  eidx = (const int*)d_in[13];

    float* out0 = (float*)d_out;
    float* out1 = out0 + (size_t)NN * 64;
    char*  ws   = (char*)d_ws;
    u16t*  wp   = (u16t*)ws;
    u16t*  nfb  = (u16t*)(ws + NFB_OFF);
    u16t*  stb  = (u16t*)(ws + STB_OFF);

    prep_k<<<PB_PACK + PB_ZERO + PB_NF + PB_ST, 256, 0, stream>>>(
        mW1, mW2, mW3, uW1, uW2, wp, (float4*)out1, nf, nfb, st, stb);
    fused_k<<<NB_EDGE + NB_NODE, 256, 0, stream>>>(
        nfb, stb, nf, ef, mb1, mb2, mb3, ub1, ub2, eidx, wp, out0, out1);
}